// Round 8
// baseline (42.870 us; speedup 1.0000x reference)
//
#include <hip/hip_runtime.h>
#include <math.h>

// Problem constants (from reference)
#define NB   64
#define CIN  3
#define PP   16      // pooled rows
#define QQ   12      // pooled cols

typedef float f32x4 __attribute__((ext_vector_type(4)));

// ---------------------------------------------------------------------------
// Kernel 1 (R7-verified): 32x32 average pooling, one WAVE per pooled output.
// 36864 outputs -> 9216 blocks x 256 threads (4 waves/block).
// Lane l reads 4 float4 (rows (l>>3)+8i, f4-col q*8+(l&7)): 8 fully-used
// 128 B segments per instruction. Register sum -> 6-step __shfl_xor reduce.
// No LDS, no __syncthreads.
// ---------------------------------------------------------------------------
__global__ __launch_bounds__(256)
void pool_kernel(const float* __restrict__ x, float* __restrict__ pooled)
{
    const int t  = threadIdx.x;
    const int o  = blockIdx.x * 4 + (t >> 6);   // global wave id = output id
    const int l  = t & 63;
    const int strip = o / QQ;
    const int q     = o - strip * QQ;

    const f32x4* base = reinterpret_cast<const f32x4*>(x) + (size_t)strip * 3072
                      + q * 8 + (l & 7);
    const int r0 = l >> 3;                      // 0..7

    f32x4 v0 = base[(r0 +  0) * 96];
    f32x4 v1 = base[(r0 +  8) * 96];
    f32x4 v2 = base[(r0 + 16) * 96];
    f32x4 v3 = base[(r0 + 24) * 96];

    float s = ((v0.x + v0.y) + (v0.z + v0.w))
            + ((v1.x + v1.y) + (v1.z + v1.w))
            + ((v2.x + v2.y) + (v2.z + v2.w))
            + ((v3.x + v3.y) + (v3.z + v3.w));

#pragma unroll
    for (int off = 32; off >= 1; off >>= 1)
        s += __shfl_xor(s, off, 64);

    if (l == 0)
        pooled[o] = s * (1.0f / 1024.0f);
}

// ---------------------------------------------------------------------------
// Kernel 2 v4: threshold -> gate -> fold (algebraic) -> projection.
// grid = 8 sample-groups x 8 feature-chunks = 64 blocks; block = 512 threads.
// Block handles 8 samples x 64 features. Thread (kc=t>>6, l=t&63):
// k-chunk [kc*72, kc*72+72), feature j = jc*64+l. Per k-step: load W once,
// feed 8 samples (8x W-reuse vs v3; W L2 traffic 75 MB -> 9.4 MB), f read
// as ds_read_b128 broadcast (4 k's), 8 independent FMA chains.
//
// folded[c][i][j] = thr[c][i][j] * G[i][j],
//   G[i][j] = sum of gate[oh][ow] over windows covering padded pos (i+1,j+1)
//   gate[oh][ow] = sigmoid((10/27) * sum_{c,kh,kw} padthr[c][2oh+kh][2ow+kw])
// ---------------------------------------------------------------------------
__global__ __launch_bounds__(512)
void head_kernel(const float* __restrict__ pooled,
                 const float* __restrict__ Wt,     // (576, 512) row-major
                 const float* __restrict__ bias,   // (512)
                 float* __restrict__ out)          // (N, 512)
{
    const int sg = blockIdx.x >> 3;  // sample group 0..7 (8 samples each)
    const int jc = blockIdx.x & 7;   // feature chunk 0..7 (64 features each)
    const int t  = threadIdx.x;
    const int l  = t & 63;           // feature lane
    const int kc = t >> 6;           // k-chunk 0..7

    __shared__ float thr[8][576];    // [s][c*192 + i*12 + j]; reused as part[]
    __shared__ float gate[8][48];    // [s][oh*6 + ow]
    __shared__ float f[8][576];      // folded, flattened (row stride 2304 B)

    // threshold: 8 samples x 576
    for (int k = t; k < 8 * 576; k += 512) {
        int s = k / 576, kk = k - s * 576;
        float p = pooled[(sg * 8 + s) * 576 + kk];
        thr[s][kk] = (p > 0.05f) ? p : 0.f;
    }
    __syncthreads();

    // gate: 8 samples x 48
    if (t < 384) {
        int s = t / 48, g = t - s * 48;
        int oh = g / 6, ow = g - oh * 6;
        float S = 0.f;
#pragma unroll
        for (int c = 0; c < 3; ++c)
#pragma unroll
            for (int kh = 0; kh < 3; ++kh)
#pragma unroll
                for (int kw = 0; kw < 3; ++kw) {
                    int r  = oh * 2 + kh - 1;   // unpadded row
                    int sx = ow * 2 + kw - 1;   // unpadded col
                    if (r >= 0 && r < PP && sx >= 0 && sx < QQ)
                        S += thr[s][c * 192 + r * 12 + sx];
                }
        gate[s][g] = 1.f / (1.f + expf(-S * (10.0f / 27.0f)));
    }
    __syncthreads();

    // f = thr * G  (8 x 576), G recomputed per (i,j)
    for (int k = t; k < 8 * 576; k += 512) {
        int s = k / 576, kk = k - s * 576;
        int ij = kk % 192;
        int i = ij / 12, j = ij - i * 12;
        int r = i + 1, sx = j + 1;             // padded coords
        float g = 0.f;
#pragma unroll
        for (int kh = 0; kh < 3; ++kh) {
            int oh2 = r - kh;
            if (oh2 < 0 || (oh2 & 1) || (oh2 >> 1) >= 8) continue;
            int oh = oh2 >> 1;
#pragma unroll
            for (int kw = 0; kw < 3; ++kw) {
                int ow2 = sx - kw;
                if (ow2 < 0 || (ow2 & 1) || (ow2 >> 1) >= 6) continue;
                g += gate[s][oh * 6 + (ow2 >> 1)];
            }
        }
        f[s][kk] = thr[s][kk] * g;
    }
    __syncthreads();

    // GEMV: thread (kc,l) -> partials for 8 samples, feature j, k in chunk.
    const int j  = jc * 64 + l;
    const int k0 = kc * 72;
    const float* Wp = Wt + (size_t)k0 * 512 + j;
    float a0 = 0.f, a1 = 0.f, a2 = 0.f, a3 = 0.f;
    float a4 = 0.f, a5 = 0.f, a6 = 0.f, a7 = 0.f;
#pragma unroll 3
    for (int kk = 0; kk < 72; kk += 4) {
        const float w0 = Wp[(size_t)(kk + 0) * 512];
        const float w1 = Wp[(size_t)(kk + 1) * 512];
        const float w2 = Wp[(size_t)(kk + 2) * 512];
        const float w3 = Wp[(size_t)(kk + 3) * 512];
#define HEAD_FMA(S, ACC)                                                   \
        {                                                                  \
            const f32x4 fv = *reinterpret_cast<const f32x4*>(&f[S][k0 + kk]); \
            ACC = fmaf(fv.x, w0, ACC);                                     \
            ACC = fmaf(fv.y, w1, ACC);                                     \
            ACC = fmaf(fv.z, w2, ACC);                                     \
            ACC = fmaf(fv.w, w3, ACC);                                     \
        }
        HEAD_FMA(0, a0) HEAD_FMA(1, a1) HEAD_FMA(2, a2) HEAD_FMA(3, a3)
        HEAD_FMA(4, a4) HEAD_FMA(5, a5) HEAD_FMA(6, a6) HEAD_FMA(7, a7)
#undef HEAD_FMA
    }

    // publish partials into the (no longer read) thr region: part[s][kc][l]
    float* part = &thr[0][0];        // 8*512 floats used
    part[0 * 512 + kc * 64 + l] = a0;
    part[1 * 512 + kc * 64 + l] = a1;
    part[2 * 512 + kc * 64 + l] = a2;
    part[3 * 512 + kc * 64 + l] = a3;
    part[4 * 512 + kc * 64 + l] = a4;
    part[5 * 512 + kc * 64 + l] = a5;
    part[6 * 512 + kc * 64 + l] = a6;
    part[7 * 512 + kc * 64 + l] = a7;
    __syncthreads();

    // reduce 8 k-chunks: thread t -> (sample s2 = t>>6, feature lane l2)
    {
        const int s2 = t >> 6;
        const int l2 = t & 63;
        float a = bias[jc * 64 + l2];
#pragma unroll
        for (int c = 0; c < 8; ++c)
            a += part[s2 * 512 + c * 64 + l2];
        out[(sg * 8 + s2) * 512 + jc * 64 + l2] = a;
    }
}

// ---------------------------------------------------------------------------
extern "C" void kernel_launch(void* const* d_in, const int* in_sizes, int n_in,
                              void* d_out, int out_size, void* d_ws, size_t ws_size,
                              hipStream_t stream)
{
    const float* x    = (const float*)d_in[0];   // (64,3,512,384) f32
    const float* Wt   = (const float*)d_in[1];   // (576,512) f32
    const float* bias = (const float*)d_in[2];   // (512,) f32
    float* out = (float*)d_out;                  // (64,512) f32
    float* pooled = (float*)d_ws;                // 64*3*16*12 = 36864 floats

    pool_kernel<<<(NB * CIN * PP * QQ) / 4, 256, 0, stream>>>(x, pooled);
    head_kernel<<<64, 512, 0, stream>>>(pooled, Wt, bias, out);
}

// Round 9
// 33.984 us; speedup vs baseline: 1.2614x; 1.2614x over previous
//
#include <hip/hip_runtime.h>
#include <math.h>

// Problem constants (from reference)
#define NB   64
#define CIN  3
#define PP   16      // pooled rows
#define QQ   12      // pooled cols

typedef float f32x4 __attribute__((ext_vector_type(4)));

// ---------------------------------------------------------------------------
// Kernel 1 v3: 32x32 average pooling, one BLOCK per contiguous 48 KB strip.
// 3072 blocks x 384 threads (6 waves). Wave w computes outputs q=2w, 2w+1.
// Lane l: f4-col q*8+(l&7), rows (l>>3)+8i (i=0..3) -> 8 loads in flight.
// Block's footprint is exactly [strip*48KB, strip*48KB+48KB): contiguous.
// Two 6-step __shfl_xor reductions; lane 0 stores both outputs.
// No LDS, no __syncthreads.
// ---------------------------------------------------------------------------
__global__ __launch_bounds__(384)
void pool_kernel(const float* __restrict__ x, float* __restrict__ pooled)
{
    const int strip = blockIdx.x;               // 0..3071
    const int t  = threadIdx.x;
    const int w  = t >> 6;                      // wave 0..5
    const int l  = t & 63;

    const f32x4* base = reinterpret_cast<const f32x4*>(x) + (size_t)strip * 3072
                      + (w * 2) * 8 + (l & 7);  // col for q0 = 2w
    const int r0 = l >> 3;                      // 0..7

    // q0 = 2w (cols +0), q1 = 2w+1 (cols +8); rows r0+8i, row stride 96 f4.
    f32x4 a0 = base[(r0 +  0) * 96 + 0];
    f32x4 a1 = base[(r0 +  8) * 96 + 0];
    f32x4 a2 = base[(r0 + 16) * 96 + 0];
    f32x4 a3 = base[(r0 + 24) * 96 + 0];
    f32x4 b0 = base[(r0 +  0) * 96 + 8];
    f32x4 b1 = base[(r0 +  8) * 96 + 8];
    f32x4 b2 = base[(r0 + 16) * 96 + 8];
    f32x4 b3 = base[(r0 + 24) * 96 + 8];

    float s0 = ((a0.x + a0.y) + (a0.z + a0.w))
             + ((a1.x + a1.y) + (a1.z + a1.w))
             + ((a2.x + a2.y) + (a2.z + a2.w))
             + ((a3.x + a3.y) + (a3.z + a3.w));
    float s1 = ((b0.x + b0.y) + (b0.z + b0.w))
             + ((b1.x + b1.y) + (b1.z + b1.w))
             + ((b2.x + b2.y) + (b2.z + b2.w))
             + ((b3.x + b3.y) + (b3.z + b3.w));

#pragma unroll
    for (int off = 32; off >= 1; off >>= 1) {
        s0 += __shfl_xor(s0, off, 64);
        s1 += __shfl_xor(s1, off, 64);
    }

    if (l == 0) {
        pooled[strip * QQ + w * 2 + 0] = s0 * (1.0f / 1024.0f);
        pooled[strip * QQ + w * 2 + 1] = s1 * (1.0f / 1024.0f);
    }
}

// ---------------------------------------------------------------------------
// Kernel 2 (R3/R7-verified v3): threshold -> gate -> fold (algebraic) -> proj.
// grid = 64 samples x 8 feature-chunks = 512 blocks; block = 512 threads.
// Thread t: l = t&63 -> feature j = jc*64+l; kc = t>>6 -> k in [kc*72,kc*72+72).
//
// folded[c][i][j] = thr[c][i][j] * G[i][j],
//   G[i][j] = sum of gate[oh][ow] over windows covering padded pos (i+1,j+1)
//   gate[oh][ow] = sigmoid((10/27) * sum_{c,kh,kw} padthr[c][2oh+kh][2ow+kw])
// ---------------------------------------------------------------------------
__global__ __launch_bounds__(512)
void head_kernel(const float* __restrict__ pooled,
                 const float* __restrict__ Wt,     // (576, 512) row-major
                 const float* __restrict__ bias,   // (512)
                 float* __restrict__ out)          // (N, 512)
{
    const int blk = blockIdx.x;      // 0..511
    const int n   = blk >> 3;        // sample 0..63
    const int jc  = blk & 7;         // feature chunk 0..7
    const int t   = threadIdx.x;
    const int l   = t & 63;          // lane -> feature jc*64+l
    const int kc  = t >> 6;          // k-chunk 0..7

    __shared__ float thr[576];       // [c*192 + i*12 + j]
    __shared__ float gate[48];       // [oh*6 + ow]
    __shared__ float f[576];         // folded, flattened
    __shared__ float part[512];      // projection partials [kc*64 + l]

    for (int k = t; k < 576; k += 512) {
        float p = pooled[n * 576 + k];
        thr[k] = (p > 0.05f) ? p : 0.f;
    }
    __syncthreads();

    if (t < 48) {
        int oh = t / 6, ow = t - oh * 6;
        float S = 0.f;
#pragma unroll
        for (int c = 0; c < 3; ++c)
#pragma unroll
            for (int kh = 0; kh < 3; ++kh)
#pragma unroll
                for (int kw = 0; kw < 3; ++kw) {
                    int r  = oh * 2 + kh - 1;   // unpadded row
                    int sx = ow * 2 + kw - 1;   // unpadded col
                    if (r >= 0 && r < PP && sx >= 0 && sx < QQ)
                        S += thr[c * 192 + r * 12 + sx];
                }
        gate[t] = 1.f / (1.f + expf(-S * (10.0f / 27.0f)));
    }
    __syncthreads();

    for (int k = t; k < 576; k += 512) {
        int ij = k % 192;
        int i = ij / 12, j = ij - i * 12;
        int r = i + 1, sx = j + 1;             // padded coords
        float g = 0.f;
#pragma unroll
        for (int kh = 0; kh < 3; ++kh) {
            int oh2 = r - kh;
            if (oh2 < 0 || (oh2 & 1) || (oh2 >> 1) >= 8) continue;
            int oh = oh2 >> 1;
#pragma unroll
            for (int kw = 0; kw < 3; ++kw) {
                int ow2 = sx - kw;
                if (ow2 < 0 || (ow2 & 1) || (ow2 >> 1) >= 6) continue;
                g += gate[oh * 6 + (ow2 >> 1)];
            }
        }
        f[k] = thr[k] * g;
    }
    __syncthreads();

    // projection partial: part[kc*64+l] = sum_{k in chunk} f[k] * Wt[k*512+j]
    const int j  = jc * 64 + l;
    const int k0 = kc * 72;
    const float* Wp = Wt + (size_t)k0 * 512 + j;
    float a0 = 0.f, a1 = 0.f, a2 = 0.f, a3 = 0.f;
#pragma unroll 6
    for (int kk = 0; kk < 72; kk += 4) {
        a0 = fmaf(f[k0 + kk + 0], Wp[(size_t)(kk + 0) * 512], a0);
        a1 = fmaf(f[k0 + kk + 1], Wp[(size_t)(kk + 1) * 512], a1);
        a2 = fmaf(f[k0 + kk + 2], Wp[(size_t)(kk + 2) * 512], a2);
        a3 = fmaf(f[k0 + kk + 3], Wp[(size_t)(kk + 3) * 512], a3);
    }
    part[t] = (a0 + a1) + (a2 + a3);
    __syncthreads();

    // reduce 8 k-chunks per feature
    if (t < 64) {
        float acc = bias[j];
#pragma unroll
        for (int c = 0; c < 8; ++c)
            acc += part[c * 64 + t];
        out[n * 512 + j] = acc;
    }
}

// ---------------------------------------------------------------------------
extern "C" void kernel_launch(void* const* d_in, const int* in_sizes, int n_in,
                              void* d_out, int out_size, void* d_ws, size_t ws_size,
                              hipStream_t stream)
{
    const float* x    = (const float*)d_in[0];   // (64,3,512,384) f32
    const float* Wt   = (const float*)d_in[1];   // (576,512) f32
    const float* bias = (const float*)d_in[2];   // (512,) f32
    float* out = (float*)d_out;                  // (64,512) f32
    float* pooled = (float*)d_ws;                // 64*3*16*12 = 36864 floats

    pool_kernel<<<NB * CIN * PP, 384, 0, stream>>>(x, pooled);
    head_kernel<<<NB * 8, 512, 0, stream>>>(pooled, Wt, bias, out);
}